// Round 1
// baseline (3359.430 us; speedup 1.0000x reference)
//
#include <hip/hip_runtime.h>

typedef unsigned short u16;
typedef __attribute__((ext_vector_type(8))) short short8;
typedef __attribute__((ext_vector_type(4))) float floatx4;

#define LDSS 40  // LDS row stride in elements for 32-wide K tiles (+8 pad, keeps 16B align)

__device__ __forceinline__ u16 f2b(float f){
  unsigned u = __builtin_bit_cast(unsigned, f);
  u += 0x7FFFu + ((u >> 16) & 1u);   // RNE; inputs are finite
  return (u16)(u >> 16);
}

__device__ __forceinline__ float gelu_f(float x){
  float u = 0.7978845608028654f * (x + 0.044715f * x * x * x);
  float e = __expf(2.0f * u);                 // tanh(u) = 1 - 2/(e+1), robust at e=inf
  return 0.5f * x * (2.0f - 2.0f / (e + 1.0f));
}

// h[b,t,c] = x[b,t,c] + wpe[t,c]
__global__ __launch_bounds__(256) void k_addpos(const float* __restrict__ x,
                                                const float* __restrict__ wpe,
                                                float* __restrict__ h){
  size_t e = ((size_t)blockIdx.x * 256 + threadIdx.x) * 4;
  float4 a = *(const float4*)(x + e);
  float4 p = *(const float4*)(wpe + (e & 1048575u)); // (row&1023)*1024 + col == e & (1M-1)
  float4 o; o.x = a.x + p.x; o.y = a.y + p.y; o.z = a.z + p.z; o.w = a.w + p.w;
  *(float4*)(h + e) = o;
}

// LayerNorm over C=1024; out bf16 (GEMM input) or fp32 (final output)
__global__ __launch_bounds__(256) void k_layernorm(const float* __restrict__ x,
                                                   const float* __restrict__ w,
                                                   const float* __restrict__ b,
                                                   void* __restrict__ out, int out_bf16){
  int row = blockIdx.x, t = threadIdx.x;
  const float* xr = x + (size_t)row * 1024;
  float4 v = ((const float4*)xr)[t];
  float s1 = v.x + v.y + v.z + v.w;
  float s2 = v.x*v.x + v.y*v.y + v.z*v.z + v.w*v.w;
  #pragma unroll
  for (int off = 32; off > 0; off >>= 1){
    s1 += __shfl_down(s1, off);
    s2 += __shfl_down(s2, off);
  }
  __shared__ float p1[4], p2[4];
  if ((t & 63) == 0){ p1[t >> 6] = s1; p2[t >> 6] = s2; }
  __syncthreads();
  float S1 = p1[0] + p1[1] + p1[2] + p1[3];
  float S2 = p2[0] + p2[1] + p2[2] + p2[3];
  float mean = S1 * (1.0f / 1024.0f);
  float var  = S2 * (1.0f / 1024.0f) - mean * mean;
  float rs = rsqrtf(var + 1e-5f);
  float4 wv = ((const float4*)w)[t];
  float4 bv = ((const float4*)b)[t];
  float o0 = (v.x - mean) * rs * wv.x + bv.x;
  float o1 = (v.y - mean) * rs * wv.y + bv.y;
  float o2 = (v.z - mean) * rs * wv.z + bv.z;
  float o3 = (v.w - mean) * rs * wv.w + bv.w;
  if (out_bf16){
    ushort4 o; o.x = f2b(o0); o.y = f2b(o1); o.z = f2b(o2); o.w = f2b(o3);
    ((ushort4*)((u16*)out + (size_t)row * 1024))[t] = o;
  } else {
    float4 o; o.x = o0; o.y = o1; o.z = o2; o.w = o3;
    ((float4*)((float*)out + (size_t)row * 1024))[t] = o;
  }
}

// 128x128 tile GEMM: C[m,n] = sum_k A[m,k] * B[n,k]  (B stored [N,K] row-major)
// A bf16; BT = float (convert on stage) or u16 (bf16).
// MODE 0: out bf16 = acc (+bias)      MODE 1: out bf16 = gelu(acc+bias)
// MODE 2: out fp32 += acc + bias      MODE 3: out fp32 = acc*scale (causal block-skip)
// causal==1: K-loop truncated at diagonal (PV). causal==2 handled by MODE 3 skip.
// grid.z decomposed as b = z>>3, h = z&7; per-z ptr offsets via *_bs (per b) / *_hs (per h).
template<typename BT, int MODE>
__global__ __launch_bounds__(256) void k_gemm(
    const u16* __restrict__ A, int lda, long long A_bs, long long A_hs,
    const BT* __restrict__ B, int ldb, long long B_bs, long long B_hs,
    const float* __restrict__ bias,
    void* __restrict__ Out, int ldo, long long O_bs, long long O_hs,
    int Kdim, float scale, int causal)
{
  int bx = blockIdx.x, by = blockIdx.y, bz = blockIdx.z;
  if (MODE == 3 && bx > by) return;   // fully-masked causal tile
  int zb = bz >> 3, zh = bz & 7;
  A += (size_t)zb * A_bs + (size_t)zh * A_hs;
  B += (size_t)zb * B_bs + (size_t)zh * B_hs;
  size_t o_off = (size_t)zb * O_bs + (size_t)zh * O_hs;
  int m0 = by * 128, n0 = bx * 128;
  __shared__ u16 As[128 * LDSS];
  __shared__ u16 Bs[128 * LDSS];
  int t = threadIdx.x;
  int lane = t & 63, wid = t >> 6;
  int wm = (wid >> 1) * 64, wn = (wid & 1) * 64;
  int quad = lane >> 4, tm = lane & 15;
  floatx4 acc[4][4] = {};
  int k_end = (causal == 1) ? (m0 + 128 < Kdim ? m0 + 128 : Kdim) : Kdim;
  for (int k0 = 0; k0 < k_end; k0 += 32){
    __syncthreads();
    { // stage A: 128x32 bf16, 16B loads
      int r = t >> 2, c = (t & 3) * 8;
      const u16* src = A + (size_t)(m0 + r) * lda + k0 + c;
      *(uint4*)&As[r * LDSS + c] = *(const uint4*)src;
      *(uint4*)&As[(r + 64) * LDSS + c] = *(const uint4*)(src + (size_t)64 * lda);
    }
    if constexpr (sizeof(BT) == 4){ // stage B fp32 -> bf16
      int r = t >> 3, c = (t & 7) * 4;
      const float* srcf = (const float*)B + (size_t)(n0 + r) * ldb + k0 + c;
      #pragma unroll
      for (int p = 0; p < 4; p++){
        float4 v = *(const float4*)(srcf + (size_t)p * 32 * ldb);
        ushort4 o; o.x = f2b(v.x); o.y = f2b(v.y); o.z = f2b(v.z); o.w = f2b(v.w);
        *(ushort4*)&Bs[(r + p * 32) * LDSS + c] = o;
      }
    } else { // stage B bf16
      int r = t >> 2, c = (t & 3) * 8;
      const u16* srcb = (const u16*)B + (size_t)(n0 + r) * ldb + k0 + c;
      *(uint4*)&Bs[r * LDSS + c] = *(const uint4*)srcb;
      *(uint4*)&Bs[(r + 64) * LDSS + c] = *(const uint4*)(srcb + (size_t)64 * ldb);
    }
    __syncthreads();
    short8 af[4], bf[4];
    #pragma unroll
    for (int i = 0; i < 4; i++)
      af[i] = *(const short8*)&As[(wm + i * 16 + tm) * LDSS + quad * 8];
    #pragma unroll
    for (int j = 0; j < 4; j++)
      bf[j] = *(const short8*)&Bs[(wn + j * 16 + tm) * LDSS + quad * 8];
    #pragma unroll
    for (int i = 0; i < 4; i++)
      #pragma unroll
      for (int j = 0; j < 4; j++)
        acc[i][j] = __builtin_amdgcn_mfma_f32_16x16x32_bf16(af[i], bf[j], acc[i][j], 0, 0, 0);
  }
  // epilogue: lane holds D[row=quad*4+r][col=tm] per 16x16 tile
  #pragma unroll
  for (int j = 0; j < 4; j++){
    int col = n0 + wn + j * 16 + tm;
    float bc = 0.0f;
    if (MODE != 3 && bias) bc = bias[col];
    #pragma unroll
    for (int i = 0; i < 4; i++){
      int row0 = m0 + wm + i * 16 + quad * 4;
      #pragma unroll
      for (int r = 0; r < 4; r++){
        float v = acc[i][j][r] + bc;
        size_t idx = o_off + (size_t)(row0 + r) * ldo + col;
        if (MODE == 0)      ((u16*)Out)[idx] = f2b(v);
        else if (MODE == 1) ((u16*)Out)[idx] = f2b(gelu_f(v));
        else if (MODE == 2) ((float*)Out)[idx] += v;
        else                ((float*)Out)[idx] = v * scale;
      }
    }
  }
}

// Vt[bh][d][s] = V[b, s, h*128+d]   (V = qkv cols [2048, 3072))
__global__ __launch_bounds__(256) void k_transpose_v(const u16* __restrict__ vsrc,
                                                     u16* __restrict__ vt){
  __shared__ u16 tile[64][66];
  int bh = blockIdx.z, b = bh >> 3, hh = bh & 7;
  int d0 = blockIdx.x * 64, s0 = blockIdx.y * 64;
  const u16* src = vsrc + (size_t)b * 3145728 + hh * 128;
  int t = threadIdx.x;
  {
    int sr = t >> 4, c4 = (t & 15) * 4;
    #pragma unroll
    for (int p = 0; p < 4; p++){
      int s = sr + p * 16;
      ushort4 v = *(const ushort4*)(src + (size_t)(s0 + s) * 3072 + d0 + c4);
      tile[s][c4 + 0] = v.x; tile[s][c4 + 1] = v.y;
      tile[s][c4 + 2] = v.z; tile[s][c4 + 3] = v.w;
    }
  }
  __syncthreads();
  {
    int dr = t >> 4, s4 = (t & 15) * 4;
    #pragma unroll
    for (int p = 0; p < 4; p++){
      int d = dr + p * 16;
      ushort4 o;
      o.x = tile[s4 + 0][d]; o.y = tile[s4 + 1][d];
      o.z = tile[s4 + 2][d]; o.w = tile[s4 + 3][d];
      *(ushort4*)(vt + (size_t)bh * 131072 + (size_t)(d0 + d) * 1024 + s0 + s4) = o;
    }
  }
}

// causal softmax over row i of S[bh]; writes P bf16 IN PLACE over the same row
// (P row j at ((u16*)Srow)[j]; P row stride = 2048 u16). All reads precede the
// first __syncthreads, all writes follow the last one -> in-place is safe.
__global__ __launch_bounds__(256) void k_softmax(float* __restrict__ S){
  int bh = blockIdx.x >> 10, i = blockIdx.x & 1023;
  float* row = S + ((size_t)bh << 20) + ((size_t)i << 10);
  int t = threadIdx.x, j0 = t * 4;
  float4 v;
  if (j0 <= i) v = ((const float4*)row)[t];
  else { v.x = 0.0f; v.y = 0.0f; v.z = 0.0f; v.w = 0.0f; }
  float mx = -3.0e38f;
  if (j0 + 0 <= i) mx = fmaxf(mx, v.x);
  if (j0 + 1 <= i) mx = fmaxf(mx, v.y);
  if (j0 + 2 <= i) mx = fmaxf(mx, v.z);
  if (j0 + 3 <= i) mx = fmaxf(mx, v.w);
  #pragma unroll
  for (int off = 32; off > 0; off >>= 1) mx = fmaxf(mx, __shfl_down(mx, off));
  __shared__ float pm[4], ps[4];
  if ((t & 63) == 0) pm[t >> 6] = mx;
  __syncthreads();
  mx = fmaxf(fmaxf(pm[0], pm[1]), fmaxf(pm[2], pm[3]));
  float e0 = (j0 + 0 <= i) ? __expf(v.x - mx) : 0.0f;
  float e1 = (j0 + 1 <= i) ? __expf(v.y - mx) : 0.0f;
  float e2 = (j0 + 2 <= i) ? __expf(v.z - mx) : 0.0f;
  float e3 = (j0 + 3 <= i) ? __expf(v.w - mx) : 0.0f;
  float s = e0 + e1 + e2 + e3;
  #pragma unroll
  for (int off = 32; off > 0; off >>= 1) s += __shfl_down(s, off);
  if ((t & 63) == 0) ps[t >> 6] = s;
  __syncthreads();
  s = ps[0] + ps[1] + ps[2] + ps[3];
  float inv = 1.0f / s;
  ushort4 o; o.x = f2b(e0 * inv); o.y = f2b(e1 * inv);
  o.z = f2b(e2 * inv); o.w = f2b(e3 * inv);
  ((ushort4*)row)[t] = o;
}

extern "C" void kernel_launch(void* const* d_in, const int* in_sizes, int n_in,
                              void* d_out, int out_size, void* d_ws, size_t ws_size,
                              hipStream_t stream){
  const float* x     = (const float*)d_in[0];
  const float* wpe   = (const float*)d_in[1];
  const float* ln1w  = (const float*)d_in[2];
  const float* ln1b  = (const float*)d_in[3];
  const float* attnw = (const float*)d_in[4];
  const float* attnb = (const float*)d_in[5];
  const float* projw = (const float*)d_in[6];
  const float* projb = (const float*)d_in[7];
  const float* ln2w  = (const float*)d_in[8];
  const float* ln2b  = (const float*)d_in[9];
  const float* fcw   = (const float*)d_in[10];
  const float* fcb   = (const float*)d_in[11];
  const float* fcpw  = (const float*)d_in[12];
  const float* fcpb  = (const float*)d_in[13];
  const float* lnfw  = (const float*)d_in[14];
  const float* lnfb  = (const float*)d_in[15];

  char* ws = (char*)d_ws;
  float* h   = (float*)(ws);               // 2048x1024 f32   (8 MB)
  u16*   xn  = (u16*)(ws + 8388608);       // 2048x1024 bf16  (4 MB)
  u16*   qkv = (u16*)(ws + 12582912);      // 2048x3072 bf16  (12 MB)
  u16*   vt  = (u16*)(ws + 25165824);      // 16x128x1024 bf16 (4 MB)
  float* S   = (float*)(ws + 29360128);    // 16x1024x1024 f32 (64 MB); P bf16 overlays rows
  u16*   yb  = (u16*)(ws + 96468992);      // 2048x1024 bf16  (4 MB)
  u16*   mlp = (u16*)(ws + 100663296);     // 2048x4096 bf16  (16 MB) -> total 112 MB

  k_addpos<<<2048, 256, 0, stream>>>(x, wpe, h);
  for (int l = 0; l < 8; l++){
    k_layernorm<<<2048, 256, 0, stream>>>(h, ln1w + l * 1024, ln1b + l * 1024, xn, 1);
    // QKV: [2048,1024] x [3072,1024]^T
    k_gemm<float, 0><<<dim3(24, 16, 1), 256, 0, stream>>>(
        xn, 1024, 0, 0, attnw + (size_t)l * 3145728, 1024, 0, 0,
        attnb + l * 3072, qkv, 3072, 0, 0, 1024, 1.0f, 0);
    k_transpose_v<<<dim3(2, 16, 16), 256, 0, stream>>>(qkv + 2048, vt);
    // scores: per (b,h): S = scale * Q @ K^T, skip above-diagonal tiles
    k_gemm<u16, 3><<<dim3(8, 8, 16), 256, 0, stream>>>(
        qkv, 3072, 3145728LL, 128LL, qkv + 1024, 3072, 3145728LL, 128LL,
        nullptr, S, 1024, 8388608LL, 1048576LL, 128, 0.08838834764831845f, 2);
    k_softmax<<<16384, 256, 0, stream>>>(S);
    // PV: per (b,h): Y = P @ V  (P bf16 overlay, lda=2048; Vt is [d][s])
    k_gemm<u16, 0><<<dim3(1, 8, 16), 256, 0, stream>>>(
        (const u16*)S, 2048, 16777216LL, 2097152LL, vt, 1024, 1048576LL, 131072LL,
        nullptr, yb, 1024, 1048576LL, 128LL, 1024, 1.0f, 1);
    // proj: h += Y @ proj_w^T + b
    k_gemm<float, 2><<<dim3(8, 16, 1), 256, 0, stream>>>(
        yb, 1024, 0, 0, projw + (size_t)l * 1048576, 1024, 0, 0,
        projb + l * 1024, h, 1024, 0, 0, 1024, 1.0f, 0);
    k_layernorm<<<2048, 256, 0, stream>>>(h, ln2w + l * 1024, ln2b + l * 1024, xn, 1);
    // fc + gelu: [2048,1024] x [4096,1024]^T
    k_gemm<float, 1><<<dim3(32, 16, 1), 256, 0, stream>>>(
        xn, 1024, 0, 0, fcw + (size_t)l * 4194304, 1024, 0, 0,
        fcb + l * 4096, mlp, 4096, 0, 0, 1024, 1.0f, 0);
    // fc_proj: h += mlp @ fcp_w^T + b
    k_gemm<float, 2><<<dim3(8, 16, 1), 256, 0, stream>>>(
        mlp, 4096, 0, 0, fcpw + (size_t)l * 4194304, 4096, 0, 0,
        fcpb + l * 1024, h, 1024, 0, 0, 4096, 1.0f, 0);
  }
  k_layernorm<<<2048, 256, 0, stream>>>(h, lnfw, lnfb, (float*)d_out, 0);
  (void)in_sizes; (void)n_in; (void)out_size; (void)ws_size;
}

// Round 2
// 2240.186 us; speedup vs baseline: 1.4996x; 1.4996x over previous
//
#include <hip/hip_runtime.h>

typedef unsigned short u16;
typedef __attribute__((ext_vector_type(8))) short short8;
typedef __attribute__((ext_vector_type(4))) float floatx4;

__device__ __forceinline__ u16 f2b(float f){
  unsigned u = __builtin_bit_cast(unsigned, f);
  u += 0x7FFFu + ((u >> 16) & 1u);   // RNE; inputs are finite
  return (u16)(u >> 16);
}

__device__ __forceinline__ float gelu_f(float x){
  float u = 0.7978845608028654f * (x + 0.044715f * x * x * x);
  float e = __expf(2.0f * u);                 // tanh(u) = 1 - 2/(e+1), robust at e=inf
  return 0.5f * x * (2.0f - 2.0f / (e + 1.0f));
}

// async global->LDS, 16B per lane (dest must be wave-uniform base + lane*16)
typedef const __attribute__((address_space(1))) unsigned int gas_u32;
typedef __attribute__((address_space(3))) unsigned int las_u32;
__device__ __forceinline__ void gll16(const void* g, void* l){
  __builtin_amdgcn_global_load_lds((gas_u32*)g, (las_u32*)l, 16, 0, 0);
}

// fp32 -> bf16 elementwise; grid = n/1024, 4 elems/thread
__global__ __launch_bounds__(256) void k_cvt(const float* __restrict__ src,
                                             u16* __restrict__ dst){
  size_t e = ((size_t)blockIdx.x * 256 + threadIdx.x) * 4;
  float4 v = *(const float4*)(src + e);
  ushort4 o; o.x = f2b(v.x); o.y = f2b(v.y); o.z = f2b(v.z); o.w = f2b(v.w);
  *(ushort4*)(dst + e) = o;
}

// h[b,t,c] = x[b,t,c] + wpe[t,c]
__global__ __launch_bounds__(256) void k_addpos(const float* __restrict__ x,
                                                const float* __restrict__ wpe,
                                                float* __restrict__ h){
  size_t e = ((size_t)blockIdx.x * 256 + threadIdx.x) * 4;
  float4 a = *(const float4*)(x + e);
  float4 p = *(const float4*)(wpe + (e & 1048575u));
  float4 o; o.x = a.x + p.x; o.y = a.y + p.y; o.z = a.z + p.z; o.w = a.w + p.w;
  *(float4*)(h + e) = o;
}

// LayerNorm over C=1024; out bf16 (GEMM input) or fp32 (final output)
__global__ __launch_bounds__(256) void k_layernorm(const float* __restrict__ x,
                                                   const float* __restrict__ w,
                                                   const float* __restrict__ b,
                                                   void* __restrict__ out, int out_bf16){
  int row = blockIdx.x, t = threadIdx.x;
  const float* xr = x + (size_t)row * 1024;
  float4 v = ((const float4*)xr)[t];
  float s1 = v.x + v.y + v.z + v.w;
  float s2 = v.x*v.x + v.y*v.y + v.z*v.z + v.w*v.w;
  #pragma unroll
  for (int off = 32; off > 0; off >>= 1){
    s1 += __shfl_down(s1, off);
    s2 += __shfl_down(s2, off);
  }
  __shared__ float p1[4], p2[4];
  if ((t & 63) == 0){ p1[t >> 6] = s1; p2[t >> 6] = s2; }
  __syncthreads();
  float S1 = p1[0] + p1[1] + p1[2] + p1[3];
  float S2 = p2[0] + p2[1] + p2[2] + p2[3];
  float mean = S1 * (1.0f / 1024.0f);
  float var  = S2 * (1.0f / 1024.0f) - mean * mean;
  float rs = rsqrtf(var + 1e-5f);
  float4 wv = ((const float4*)w)[t];
  float4 bv = ((const float4*)b)[t];
  float o0 = (v.x - mean) * rs * wv.x + bv.x;
  float o1 = (v.y - mean) * rs * wv.y + bv.y;
  float o2 = (v.z - mean) * rs * wv.z + bv.z;
  float o3 = (v.w - mean) * rs * wv.w + bv.w;
  if (out_bf16){
    ushort4 o; o.x = f2b(o0); o.y = f2b(o1); o.z = f2b(o2); o.w = f2b(o3);
    ((ushort4*)((u16*)out + (size_t)row * 1024))[t] = o;
  } else {
    float4 o; o.x = o0; o.y = o1; o.z = o2; o.w = o3;
    ((float4*)((float*)out + (size_t)row * 1024))[t] = o;
  }
}

// 128x128x(BK=32) bf16 GEMM, m97 structure: unpadded LDS + global_load_lds x16.
// C[m,n] = sum_k A[m,k]*B[n,k]  (both operands [rows, K] row-major bf16)
// MODE 0: bf16 = acc + bias            MODE 1: bf16 = gelu(acc + bias)
// MODE 2: fp32 atomicAdd(acc [+bias if split 0])   (residual h += ...)
// MODE 3: fp32 = acc * scale, causal block-skip (scores)
// MODE 4: fp32 atomicAdd(acc)          (PV partial sums)
// Split-K: bx -> nt = bx % n_ntiles (N tile), sp = bx / n_ntiles (K chunk).
// causal==1: effective K truncated at diagonal (m0+128).
template<int MODE>
__global__ __launch_bounds__(256) void k_gemm(
    const u16* __restrict__ A, int lda, long long A_bs, long long A_hs,
    const u16* __restrict__ B, int ldb, long long B_bs, long long B_hs,
    const float* __restrict__ bias,
    void* __restrict__ Out, int ldo, long long O_bs, long long O_hs,
    int Kdim, float scale, int causal, int n_ntiles, int Ksplit)
{
  int bx = blockIdx.x, by = blockIdx.y, bz = blockIdx.z;
  int nt = bx % n_ntiles, sp = bx / n_ntiles;
  if (MODE == 3 && nt > by) return;          // fully-masked causal tile
  int m0 = by * 128, n0 = nt * 128;
  int kend_eff = (causal == 1) ? (m0 + 128 < Kdim ? m0 + 128 : Kdim) : Kdim;
  int ks = sp * Ksplit;
  int ke = ks + Ksplit < kend_eff ? ks + Ksplit : kend_eff;
  if (ks >= ke) return;
  int zb = bz >> 3, zh = bz & 7;
  A += (size_t)zb * A_bs + (size_t)zh * A_hs;
  B += (size_t)zb * B_bs + (size_t)zh * B_hs;
  size_t o_off = (size_t)zb * O_bs + (size_t)zh * O_hs;

  __shared__ u16 As[128 * 32];
  __shared__ u16 Bs[128 * 32];
  int t = threadIdx.x;
  int lane = t & 63, wid = t >> 6;
  int wm = (wid >> 1) * 64, wn = (wid & 1) * 64;
  int quad = lane >> 4, tm = lane & 15;
  // staging: chunk t covers LDS elems [t*8, t*8+8) -> tile row t>>2, col (t&3)*8
  int ar = t >> 2, ac = (t & 3) * 8;
  const u16* Ab = A + (size_t)(m0 + ar) * lda + ac;
  const u16* Bb = B + (size_t)(n0 + ar) * ldb + ac;
  u16* AsP0 = &As[t * 8];           u16* AsP1 = &As[2048 + t * 8];
  u16* BsP0 = &Bs[t * 8];           u16* BsP1 = &Bs[2048 + t * 8];
  const size_t a64 = (size_t)64 * lda, b64 = (size_t)64 * ldb;

  floatx4 acc[4][4] = {};
  for (int k0 = ks; k0 < ke; k0 += 32){
    __syncthreads();
    gll16(Ab + k0,        AsP0);
    gll16(Ab + a64 + k0,  AsP1);
    gll16(Bb + k0,        BsP0);
    gll16(Bb + b64 + k0,  BsP1);
    __syncthreads();
    short8 af[4], bf[4];
    #pragma unroll
    for (int i = 0; i < 4; i++)
      af[i] = *(const short8*)&As[(wm + i * 16 + tm) * 32 + quad * 8];
    #pragma unroll
    for (int j = 0; j < 4; j++)
      bf[j] = *(const short8*)&Bs[(wn + j * 16 + tm) * 32 + quad * 8];
    #pragma unroll
    for (int i = 0; i < 4; i++)
      #pragma unroll
      for (int j = 0; j < 4; j++)
        acc[i][j] = __builtin_amdgcn_mfma_f32_16x16x32_bf16(af[i], bf[j], acc[i][j], 0, 0, 0);
  }
  // epilogue: lane holds D[row=quad*4+r][col=tm] per 16x16 tile
  #pragma unroll
  for (int j = 0; j < 4; j++){
    int col = n0 + wn + j * 16 + tm;
    float bc = 0.0f;
    if ((MODE == 0 || MODE == 1) && bias) bc = bias[col];
    if (MODE == 2 && sp == 0 && bias) bc = bias[col];
    #pragma unroll
    for (int i = 0; i < 4; i++){
      int row0 = m0 + wm + i * 16 + quad * 4;
      #pragma unroll
      for (int r = 0; r < 4; r++){
        float v = acc[i][j][r] + bc;
        size_t idx = o_off + (size_t)(row0 + r) * ldo + col;
        if (MODE == 0)      ((u16*)Out)[idx] = f2b(v);
        else if (MODE == 1) ((u16*)Out)[idx] = f2b(gelu_f(v));
        else if (MODE == 3) ((float*)Out)[idx] = v * scale;
        else                atomicAdd((float*)Out + idx, v);
      }
    }
  }
}

// Vt[bh][d][s] = V[b, s, h*128+d]   (V = qkv cols [2048, 3072))
__global__ __launch_bounds__(256) void k_transpose_v(const u16* __restrict__ vsrc,
                                                     u16* __restrict__ vt){
  __shared__ u16 tile[64][66];
  int bh = blockIdx.z, b = bh >> 3, hh = bh & 7;
  int d0 = blockIdx.x * 64, s0 = blockIdx.y * 64;
  const u16* src = vsrc + (size_t)b * 3145728 + hh * 128;
  int t = threadIdx.x;
  {
    int sr = t >> 4, c4 = (t & 15) * 4;
    #pragma unroll
    for (int p = 0; p < 4; p++){
      int s = sr + p * 16;
      ushort4 v = *(const ushort4*)(src + (size_t)(s0 + s) * 3072 + d0 + c4);
      tile[s][c4 + 0] = v.x; tile[s][c4 + 1] = v.y;
      tile[s][c4 + 2] = v.z; tile[s][c4 + 3] = v.w;
    }
  }
  __syncthreads();
  {
    int dr = t >> 4, s4 = (t & 15) * 4;
    #pragma unroll
    for (int p = 0; p < 4; p++){
      int d = dr + p * 16;
      ushort4 o;
      o.x = tile[s4 + 0][d]; o.y = tile[s4 + 1][d];
      o.z = tile[s4 + 2][d]; o.w = tile[s4 + 3][d];
      *(ushort4*)(vt + (size_t)bh * 131072 + (size_t)(d0 + d) * 1024 + s0 + s4) = o;
    }
  }
}

// causal softmax over row i of S[bh]; writes P bf16 IN PLACE over the same row
__global__ __launch_bounds__(256) void k_softmax(float* __restrict__ S){
  int bh = blockIdx.x >> 10, i = blockIdx.x & 1023;
  float* row = S + ((size_t)bh << 20) + ((size_t)i << 10);
  int t = threadIdx.x, j0 = t * 4;
  float4 v;
  if (j0 <= i) v = ((const float4*)row)[t];
  else { v.x = 0.0f; v.y = 0.0f; v.z = 0.0f; v.w = 0.0f; }
  float mx = -3.0e38f;
  if (j0 + 0 <= i) mx = fmaxf(mx, v.x);
  if (j0 + 1 <= i) mx = fmaxf(mx, v.y);
  if (j0 + 2 <= i) mx = fmaxf(mx, v.z);
  if (j0 + 3 <= i) mx = fmaxf(mx, v.w);
  #pragma unroll
  for (int off = 32; off > 0; off >>= 1) mx = fmaxf(mx, __shfl_down(mx, off));
  __shared__ float pm[4], ps[4];
  if ((t & 63) == 0) pm[t >> 6] = mx;
  __syncthreads();
  mx = fmaxf(fmaxf(pm[0], pm[1]), fmaxf(pm[2], pm[3]));
  float e0 = (j0 + 0 <= i) ? __expf(v.x - mx) : 0.0f;
  float e1 = (j0 + 1 <= i) ? __expf(v.y - mx) : 0.0f;
  float e2 = (j0 + 2 <= i) ? __expf(v.z - mx) : 0.0f;
  float e3 = (j0 + 3 <= i) ? __expf(v.w - mx) : 0.0f;
  float s = e0 + e1 + e2 + e3;
  #pragma unroll
  for (int off = 32; off > 0; off >>= 1) s += __shfl_down(s, off);
  if ((t & 63) == 0) ps[t >> 6] = s;
  __syncthreads();
  s = ps[0] + ps[1] + ps[2] + ps[3];
  float inv = 1.0f / s;
  ushort4 o; o.x = f2b(e0 * inv); o.y = f2b(e1 * inv);
  o.z = f2b(e2 * inv); o.w = f2b(e3 * inv);
  ((ushort4*)row)[t] = o;
}

extern "C" void kernel_launch(void* const* d_in, const int* in_sizes, int n_in,
                              void* d_out, int out_size, void* d_ws, size_t ws_size,
                              hipStream_t stream){
  const float* x     = (const float*)d_in[0];
  const float* wpe   = (const float*)d_in[1];
  const float* ln1w  = (const float*)d_in[2];
  const float* ln1b  = (const float*)d_in[3];
  const float* attnw = (const float*)d_in[4];
  const float* attnb = (const float*)d_in[5];
  const float* projw = (const float*)d_in[6];
  const float* projb = (const float*)d_in[7];
  const float* ln2w  = (const float*)d_in[8];
  const float* ln2b  = (const float*)d_in[9];
  const float* fcw   = (const float*)d_in[10];
  const float* fcb   = (const float*)d_in[11];
  const float* fcpw  = (const float*)d_in[12];
  const float* fcpb  = (const float*)d_in[13];
  const float* lnfw  = (const float*)d_in[14];
  const float* lnfb  = (const float*)d_in[15];

  char* ws = (char*)d_ws;
  float* h   = (float*)(ws);               // 2048x1024 f32   (8 MB)
  u16*   xn  = (u16*)(ws + 8388608);       // 2048x1024 bf16  (4 MB)
  u16*   qkv = (u16*)(ws + 12582912);      // 2048x3072 bf16  (12 MB)
  u16*   vt  = (u16*)(ws + 25165824);      // 16x128x1024 bf16 (4 MB)
  float* S   = (float*)(ws + 29360128);    // 16x1024x1024 f32 (64 MB); P bf16 overlays rows
  u16*   yb  = (u16*)(ws + 29360128);      // 2048x1024 bf16  (4 MB) — overlays dead S
  u16*   mlp = (u16*)(ws + 33554432);      // 2048x4096 bf16  (16 MB) — overlays dead S
  float* ybf = (float*)(ws + 96468992);    // 2048x1024 f32   (8 MB) PV split-K accum
  u16*   wb  = (u16*)(ws + 104857600);     // bf16 weight buf (8 MB) -> total 108 MB

  k_addpos<<<2048, 256, 0, stream>>>(x, wpe, h);
  for (int l = 0; l < 8; l++){
    k_layernorm<<<2048, 256, 0, stream>>>(h, ln1w + l * 1024, ln1b + l * 1024, xn, 1);
    // QKV: [2048,1024] x [3072,1024]^T
    k_cvt<<<3072, 256, 0, stream>>>(attnw + (size_t)l * 3145728, wb);
    k_gemm<0><<<dim3(24, 16, 1), 256, 0, stream>>>(
        xn, 1024, 0, 0, wb, 1024, 0, 0, attnb + l * 3072,
        qkv, 3072, 0, 0, 1024, 1.0f, 0, 24, 1024);
    k_transpose_v<<<dim3(2, 16, 16), 256, 0, stream>>>(qkv + 2048, vt);
    // scores: per (b,h): S = scale * Q @ K^T, skip above-diagonal tiles
    k_gemm<3><<<dim3(8, 8, 16), 256, 0, stream>>>(
        qkv, 3072, 3145728LL, 128LL, qkv + 1024, 3072, 3145728LL, 128LL,
        nullptr, S, 1024, 8388608LL, 1048576LL, 128, 0.08838834764831845f, 2, 8, 128);
    k_softmax<<<16384, 256, 0, stream>>>(S);
    // PV: per (b,h): Ybf = P @ V, split-K x4 (causal-truncated), fp32 atomics
    hipMemsetAsync(ybf, 0, 8388608, stream);
    k_gemm<4><<<dim3(4, 8, 16), 256, 0, stream>>>(
        (const u16*)S, 2048, 16777216LL, 2097152LL, vt, 1024, 1048576LL, 131072LL,
        nullptr, ybf, 1024, 1048576LL, 128LL, 1024, 1.0f, 1, 1, 256);
    k_cvt<<<2048, 256, 0, stream>>>(ybf, yb);
    // proj: h += Y @ proj_w^T + b, split-K x4
    k_cvt<<<1024, 256, 0, stream>>>(projw + (size_t)l * 1048576, wb);
    k_gemm<2><<<dim3(32, 16, 1), 256, 0, stream>>>(
        yb, 1024, 0, 0, wb, 1024, 0, 0, projb + l * 1024,
        h, 1024, 0, 0, 1024, 1.0f, 0, 8, 256);
    k_layernorm<<<2048, 256, 0, stream>>>(h, ln2w + l * 1024, ln2b + l * 1024, xn, 1);
    // fc + gelu: [2048,1024] x [4096,1024]^T
    k_cvt<<<4096, 256, 0, stream>>>(fcw + (size_t)l * 4194304, wb);
    k_gemm<1><<<dim3(32, 16, 1), 256, 0, stream>>>(
        xn, 1024, 0, 0, wb, 1024, 0, 0, fcb + l * 4096,
        mlp, 4096, 0, 0, 1024, 1.0f, 0, 32, 1024);
    // fc_proj: h += mlp @ fcp_w^T + b, split-K x4
    k_cvt<<<4096, 256, 0, stream>>>(fcpw + (size_t)l * 4194304, wb);
    k_gemm<2><<<dim3(32, 16, 1), 256, 0, stream>>>(
        mlp, 4096, 0, 0, wb, 4096, 0, 0, fcpb + l * 1024,
        h, 1024, 0, 0, 4096, 1.0f, 0, 8, 1024);
  }
  k_layernorm<<<2048, 256, 0, stream>>>(h, lnfw, lnfb, (float*)d_out, 0);
  (void)in_sizes; (void)n_in; (void)out_size; (void)ws_size;
}

// Round 3
// 2133.475 us; speedup vs baseline: 1.5746x; 1.0500x over previous
//
#include <hip/hip_runtime.h>

typedef unsigned short u16;
typedef __attribute__((ext_vector_type(8))) short short8;
typedef __attribute__((ext_vector_type(4))) float floatx4;

__device__ __forceinline__ u16 f2b(float f){
  unsigned u = __builtin_bit_cast(unsigned, f);
  u += 0x7FFFu + ((u >> 16) & 1u);   // RNE; inputs are finite
  return (u16)(u >> 16);
}

__device__ __forceinline__ float gelu_f(float x){
  float u = 0.7978845608028654f * (x + 0.044715f * x * x * x);
  float e = __expf(2.0f * u);                 // tanh(u) = 1 - 2/(e+1), robust at e=inf
  return 0.5f * x * (2.0f - 2.0f / (e + 1.0f));
}

// async global->LDS, 16B per lane (LDS dest = wave-uniform base + lane*16)
typedef const __attribute__((address_space(1))) unsigned int gas_u32;
typedef __attribute__((address_space(3))) unsigned int las_u32;
__device__ __forceinline__ void gll16(const void* g, void* l){
  __builtin_amdgcn_global_load_lds((gas_u32*)g, (las_u32*)l, 16, 0, 0);
}

// fp32 -> bf16 elementwise; 4 elems/thread
__global__ __launch_bounds__(256) void k_cvt(const float* __restrict__ src,
                                             u16* __restrict__ dst){
  size_t e = ((size_t)blockIdx.x * 256 + threadIdx.x) * 4;
  float4 v = *(const float4*)(src + e);
  ushort4 o; o.x = f2b(v.x); o.y = f2b(v.y); o.z = f2b(v.z); o.w = f2b(v.w);
  *(ushort4*)(dst + e) = o;
}

// h[b,t,c] = x[b,t,c] + wpe[t,c]
__global__ __launch_bounds__(256) void k_addpos(const float* __restrict__ x,
                                                const float* __restrict__ wpe,
                                                float* __restrict__ h){
  size_t e = ((size_t)blockIdx.x * 256 + threadIdx.x) * 4;
  float4 a = *(const float4*)(x + e);
  float4 p = *(const float4*)(wpe + (e & 1048575u));
  float4 o; o.x = a.x + p.x; o.y = a.y + p.y; o.z = a.z + p.z; o.w = a.w + p.w;
  *(float4*)(h + e) = o;
}

// LayerNorm over C=1024; out bf16 (GEMM input) or fp32 (final output)
__global__ __launch_bounds__(256) void k_layernorm(const float* __restrict__ x,
                                                   const float* __restrict__ w,
                                                   const float* __restrict__ b,
                                                   void* __restrict__ out, int out_bf16){
  int row = blockIdx.x, t = threadIdx.x;
  const float* xr = x + (size_t)row * 1024;
  float4 v = ((const float4*)xr)[t];
  float s1 = v.x + v.y + v.z + v.w;
  float s2 = v.x*v.x + v.y*v.y + v.z*v.z + v.w*v.w;
  #pragma unroll
  for (int off = 32; off > 0; off >>= 1){
    s1 += __shfl_down(s1, off);
    s2 += __shfl_down(s2, off);
  }
  __shared__ float p1[4], p2[4];
  if ((t & 63) == 0){ p1[t >> 6] = s1; p2[t >> 6] = s2; }
  __syncthreads();
  float S1 = p1[0] + p1[1] + p1[2] + p1[3];
  float S2 = p2[0] + p2[1] + p2[2] + p2[3];
  float mean = S1 * (1.0f / 1024.0f);
  float var  = S2 * (1.0f / 1024.0f) - mean * mean;
  float rs = rsqrtf(var + 1e-5f);
  float4 wv = ((const float4*)w)[t];
  float4 bv = ((const float4*)b)[t];
  float o0 = (v.x - mean) * rs * wv.x + bv.x;
  float o1 = (v.y - mean) * rs * wv.y + bv.y;
  float o2 = (v.z - mean) * rs * wv.z + bv.z;
  float o3 = (v.w - mean) * rs * wv.w + bv.w;
  if (out_bf16){
    ushort4 o; o.x = f2b(o0); o.y = f2b(o1); o.z = f2b(o2); o.w = f2b(o3);
    ((ushort4*)((u16*)out + (size_t)row * 1024))[t] = o;
  } else {
    float4 o; o.x = o0; o.y = o1; o.z = o2; o.w = o3;
    ((float4*)((float*)out + (size_t)row * 1024))[t] = o;
  }
}

// 128x128x(BK=32) bf16 GEMM, m97 structure: unpadded LDS + global_load_lds x16.
// C[m,n] = sum_k A[m,k]*B[n,k]  (both operands [rows, K] row-major bf16)
// MODE 0: bf16 = acc + bias    MODE 1: bf16 = gelu(acc + bias)
// MODE 2: fp32 atomicAdd(acc [+bias if sp==0])   (residual h += ...)
// Split-K: bx -> nt = bx % n_ntiles (N tile), sp = bx / n_ntiles (K chunk).
template<int MODE>
__global__ __launch_bounds__(256) void k_gemm(
    const u16* __restrict__ A, int lda,
    const u16* __restrict__ B, int ldb,
    const float* __restrict__ bias,
    void* __restrict__ Out, int ldo,
    int Kdim, int n_ntiles, int Ksplit)
{
  int bx = blockIdx.x, by = blockIdx.y;
  int nt = bx % n_ntiles, sp = bx / n_ntiles;
  int m0 = by * 128, n0 = nt * 128;
  int ks = sp * Ksplit;
  int ke = ks + Ksplit < Kdim ? ks + Ksplit : Kdim;
  if (ks >= ke) return;

  __shared__ u16 As[128 * 32];
  __shared__ u16 Bs[128 * 32];
  int t = threadIdx.x;
  int lane = t & 63, wid = t >> 6;
  int wm = (wid >> 1) * 64, wn = (wid & 1) * 64;
  int quad = lane >> 4, tm = lane & 15;
  int ar = t >> 2, ac = (t & 3) * 8;
  const u16* Ab = A + (size_t)(m0 + ar) * lda + ac;
  const u16* Bb = B + (size_t)(n0 + ar) * ldb + ac;
  u16* AsP0 = &As[t * 8];           u16* AsP1 = &As[2048 + t * 8];
  u16* BsP0 = &Bs[t * 8];           u16* BsP1 = &Bs[2048 + t * 8];
  const size_t a64 = (size_t)64 * lda, b64 = (size_t)64 * ldb;

  floatx4 acc[4][4] = {};
  for (int k0 = ks; k0 < ke; k0 += 32){
    __syncthreads();
    gll16(Ab + k0,        AsP0);
    gll16(Ab + a64 + k0,  AsP1);
    gll16(Bb + k0,        BsP0);
    gll16(Bb + b64 + k0,  BsP1);
    __syncthreads();
    short8 af[4], bf[4];
    #pragma unroll
    for (int i = 0; i < 4; i++)
      af[i] = *(const short8*)&As[(wm + i * 16 + tm) * 32 + quad * 8];
    #pragma unroll
    for (int j = 0; j < 4; j++)
      bf[j] = *(const short8*)&Bs[(wn + j * 16 + tm) * 32 + quad * 8];
    #pragma unroll
    for (int i = 0; i < 4; i++)
      #pragma unroll
      for (int j = 0; j < 4; j++)
        acc[i][j] = __builtin_amdgcn_mfma_f32_16x16x32_bf16(af[i], bf[j], acc[i][j], 0, 0, 0);
  }
  #pragma unroll
  for (int j = 0; j < 4; j++){
    int col = n0 + wn + j * 16 + tm;
    float bc = 0.0f;
    if ((MODE == 0 || MODE == 1) && bias) bc = bias[col];
    if (MODE == 2 && sp == 0 && bias) bc = bias[col];
    #pragma unroll
    for (int i = 0; i < 4; i++){
      int row0 = m0 + wm + i * 16 + quad * 4;
      #pragma unroll
      for (int r = 0; r < 4; r++){
        float v = acc[i][j][r] + bc;
        size_t idx = (size_t)(row0 + r) * ldo + col;
        if (MODE == 0)      ((u16*)Out)[idx] = f2b(v);
        else if (MODE == 1) ((u16*)Out)[idx] = f2b(gelu_f(v));
        else                atomicAdd((float*)Out + idx, v);
      }
    }
  }
}

// Vt[bh][d][s] = V[b, s, h*128+d]   (V = qkv cols [2048, 3072))
__global__ __launch_bounds__(256) void k_transpose_v(const u16* __restrict__ vsrc,
                                                     u16* __restrict__ vt){
  __shared__ u16 tile[64][66];
  int bh = blockIdx.z, b = bh >> 3, hh = bh & 7;
  int d0 = blockIdx.x * 64, s0 = blockIdx.y * 64;
  const u16* src = vsrc + (size_t)b * 3145728 + hh * 128;
  int t = threadIdx.x;
  {
    int sr = t >> 4, c4 = (t & 15) * 4;
    #pragma unroll
    for (int p = 0; p < 4; p++){
      int s = sr + p * 16;
      ushort4 v = *(const ushort4*)(src + (size_t)(s0 + s) * 3072 + d0 + c4);
      tile[s][c4 + 0] = v.x; tile[s][c4 + 1] = v.y;
      tile[s][c4 + 2] = v.z; tile[s][c4 + 3] = v.w;
    }
  }
  __syncthreads();
  {
    int dr = t >> 4, s4 = (t & 15) * 4;
    #pragma unroll
    for (int p = 0; p < 4; p++){
      int d = dr + p * 16;
      ushort4 o;
      o.x = tile[s4 + 0][d]; o.y = tile[s4 + 1][d];
      o.z = tile[s4 + 2][d]; o.w = tile[s4 + 3][d];
      *(ushort4*)(vt + (size_t)bh * 131072 + (size_t)(d0 + d) * 1024 + s0 + s4) = o;
    }
  }
}

// Fused causal flash attention. Grid (16 q-tiles of 64 rows, 16 b*h).
// Per wave: 16 q-rows x full d=128. Q in regs; K/Vt tiles staged to LDS;
// P round-trips C-layout -> LDS -> A-layout (per-wave private region).
__global__ __launch_bounds__(256) void k_flash(const u16* __restrict__ qkv,
                                               const u16* __restrict__ vt,
                                               u16* __restrict__ yb){
  int qi = blockIdx.x, bh = blockIdx.y;
  int b = bh >> 3, hh = bh & 7;
  int t = threadIdx.x, lane = t & 63, w = t >> 6;
  int quad = lane >> 4, tm = lane & 15;
  const int q0 = qi * 64;
  const u16* Qg  = qkv + (size_t)b * 3145728 + hh * 128;   // + row*3072
  const u16* Kg  = Qg + 1024;
  const u16* Vtg = vt + (size_t)bh * 131072;               // [d][s], ld=1024
  __shared__ u16 Ks[64 * 128];
  __shared__ u16 Vs[128 * 64];
  __shared__ u16 Ps[4][16 * 64];

  short8 qf[4];
  {
    const u16* qr = Qg + (size_t)(q0 + w * 16 + tm) * 3072 + quad * 8;
    #pragma unroll
    for (int kk = 0; kk < 4; kk++) qf[kk] = *(const short8*)(qr + kk * 32);
  }
  floatx4 o_acc[8] = {};
  float m_r[4], l_r[4];
  #pragma unroll
  for (int r = 0; r < 4; r++){ m_r[r] = -3.0e38f; l_r[r] = 0.0f; }
  const float scale = 0.08838834764831845f;

  for (int s0 = 0; s0 <= q0; s0 += 64){
    __syncthreads();
    {
      int idx = w * 256 + lane;
      #pragma unroll
      for (int p = 0; p < 4; p++){       // K tile: Ks[s(64)][d(128)]
        int id = idx + p * 64;
        gll16(Kg + (size_t)(s0 + (id >> 4)) * 3072 + (id & 15) * 8, &Ks[id * 8]);
      }
      #pragma unroll
      for (int p = 0; p < 4; p++){       // Vt tile: Vs[d(128)][s(64)]
        int id = idx + p * 64;
        gll16(Vtg + (size_t)(id >> 3) * 1024 + s0 + (id & 7) * 8, &Vs[id * 8]);
      }
    }
    __syncthreads();
    floatx4 s_acc[4] = {};
    #pragma unroll
    for (int j = 0; j < 4; j++)
      #pragma unroll
      for (int kk = 0; kk < 4; kk++){
        short8 kf = *(const short8*)&Ks[(j * 16 + tm) * 128 + kk * 32 + quad * 8];
        s_acc[j] = __builtin_amdgcn_mfma_f32_16x16x32_bf16(qf[kk], kf, s_acc[j], 0, 0, 0);
      }
    bool diag = (s0 == q0);
    float sv[4][4];
    #pragma unroll
    for (int j = 0; j < 4; j++)
      #pragma unroll
      for (int r = 0; r < 4; r++){
        float v = s_acc[j][r] * scale;
        if (diag && (j * 16 + tm > w * 16 + quad * 4 + r)) v = -3.0e38f;
        sv[j][r] = v;
      }
    float pv[4][4];
    #pragma unroll
    for (int r = 0; r < 4; r++){
      float m = fmaxf(fmaxf(sv[0][r], sv[1][r]), fmaxf(sv[2][r], sv[3][r]));
      #pragma unroll
      for (int off = 8; off > 0; off >>= 1) m = fmaxf(m, __shfl_xor(m, off));
      float m_new = fmaxf(m_r[r], m);
      float alpha = __expf(m_r[r] - m_new);
      m_r[r] = m_new;
      float s = 0.0f;
      #pragma unroll
      for (int j = 0; j < 4; j++){
        float p = __expf(sv[j][r] - m_new);
        pv[j][r] = p; s += p;
      }
      #pragma unroll
      for (int off = 8; off > 0; off >>= 1) s += __shfl_xor(s, off);
      l_r[r] = l_r[r] * alpha + s;
      #pragma unroll
      for (int jd = 0; jd < 8; jd++) o_acc[jd][r] *= alpha;
    }
    // P: C-layout regs -> per-wave LDS -> A-layout frags
    u16* Pw = Ps[w];
    #pragma unroll
    for (int j = 0; j < 4; j++)
      #pragma unroll
      for (int r = 0; r < 4; r++)
        Pw[(quad * 4 + r) * 64 + j * 16 + tm] = f2b(pv[j][r]);
    __syncthreads();
    short8 pf[2];
    #pragma unroll
    for (int kk = 0; kk < 2; kk++)
      pf[kk] = *(const short8*)&Pw[tm * 64 + kk * 32 + quad * 8];
    #pragma unroll
    for (int jd = 0; jd < 8; jd++)
      #pragma unroll
      for (int kk = 0; kk < 2; kk++){
        short8 vf = *(const short8*)&Vs[(jd * 16 + tm) * 64 + kk * 32 + quad * 8];
        o_acc[jd] = __builtin_amdgcn_mfma_f32_16x16x32_bf16(pf[kk], vf, o_acc[jd], 0, 0, 0);
      }
  }
  u16* yr = yb + ((size_t)b * 1024 + q0 + w * 16 + quad * 4) * 1024 + hh * 128;
  #pragma unroll
  for (int r = 0; r < 4; r++){
    float inv = 1.0f / l_r[r];
    #pragma unroll
    for (int jd = 0; jd < 8; jd++)
      yr[(size_t)r * 1024 + jd * 16 + tm] = f2b(o_acc[jd][r] * inv);
  }
}

extern "C" void kernel_launch(void* const* d_in, const int* in_sizes, int n_in,
                              void* d_out, int out_size, void* d_ws, size_t ws_size,
                              hipStream_t stream){
  const float* x     = (const float*)d_in[0];
  const float* wpe   = (const float*)d_in[1];
  const float* ln1w  = (const float*)d_in[2];
  const float* ln1b  = (const float*)d_in[3];
  const float* attnw = (const float*)d_in[4];
  const float* attnb = (const float*)d_in[5];
  const float* projw = (const float*)d_in[6];
  const float* projb = (const float*)d_in[7];
  const float* ln2w  = (const float*)d_in[8];
  const float* ln2b  = (const float*)d_in[9];
  const float* fcw   = (const float*)d_in[10];
  const float* fcb   = (const float*)d_in[11];
  const float* fcpw  = (const float*)d_in[12];
  const float* fcpb  = (const float*)d_in[13];
  const float* lnfw  = (const float*)d_in[14];
  const float* lnfb  = (const float*)d_in[15];

  char* ws = (char*)d_ws;                  // ws_size ~512 MB; we use 240 MB
  float* h    = (float*)(ws);              // 2048x1024 f32   (8 MB)
  u16*   xn   = (u16*)(ws + 8388608);      // 2048x1024 bf16  (4 MB)
  u16*   qkv  = (u16*)(ws + 12582912);     // 2048x3072 bf16  (12 MB)
  u16*   vt   = (u16*)(ws + 25165824);     // 16x128x1024 bf16 (4 MB)
  u16*   yb   = (u16*)(ws + 29360128);     // 2048x1024 bf16  (4 MB)
  u16*   mlp  = (u16*)(ws + 33554432);     // 2048x4096 bf16  (16 MB)
  u16*   wqkv = (u16*)(ws + 50331648);     // 8 x 3072x1024 bf16 (48 MB)
  u16*   wprj = (u16*)(ws + 100663296);    // 8 x 1024x1024 bf16 (16 MB)
  u16*   wfc  = (u16*)(ws + 117440512);    // 8 x 4096x1024 bf16 (64 MB)
  u16*   wfcp = (u16*)(ws + 184549376);    // 8 x 1024x4096 bf16 (64 MB) -> 240 MB

  // one-shot weight conversion (all layers)
  k_cvt<<<24576, 256, 0, stream>>>(attnw, wqkv);
  k_cvt<<<8192,  256, 0, stream>>>(projw, wprj);
  k_cvt<<<32768, 256, 0, stream>>>(fcw,  wfc);
  k_cvt<<<32768, 256, 0, stream>>>(fcpw, wfcp);
  k_addpos<<<2048, 256, 0, stream>>>(x, wpe, h);

  for (int l = 0; l < 8; l++){
    k_layernorm<<<2048, 256, 0, stream>>>(h, ln1w + l * 1024, ln1b + l * 1024, xn, 1);
    // QKV: [2048,1024] x [3072,1024]^T -> bf16 + bias
    k_gemm<0><<<dim3(24, 16), 256, 0, stream>>>(
        xn, 1024, wqkv + (size_t)l * 3145728, 1024, attnb + l * 3072,
        qkv, 3072, 1024, 24, 1024);
    k_transpose_v<<<dim3(2, 16, 16), 256, 0, stream>>>(qkv + 2048, vt);
    k_flash<<<dim3(16, 16), 256, 0, stream>>>(qkv, vt, yb);
    // proj: h += Y @ proj_w^T + b, split-K x4
    k_gemm<2><<<dim3(32, 16), 256, 0, stream>>>(
        yb, 1024, wprj + (size_t)l * 1048576, 1024, projb + l * 1024,
        h, 1024, 1024, 8, 256);
    k_layernorm<<<2048, 256, 0, stream>>>(h, ln2w + l * 1024, ln2b + l * 1024, xn, 1);
    // fc + gelu: [2048,1024] x [4096,1024]^T
    k_gemm<1><<<dim3(32, 16), 256, 0, stream>>>(
        xn, 1024, wfc + (size_t)l * 4194304, 1024, fcb + l * 4096,
        mlp, 4096, 1024, 32, 1024);
    // fc_proj: h += mlp @ fcp_w^T + b, split-K x4
    k_gemm<2><<<dim3(32, 16), 256, 0, stream>>>(
        mlp, 4096, wfcp + (size_t)l * 4194304, 4096, fcpb + l * 1024,
        h, 1024, 4096, 8, 1024);
  }
  k_layernorm<<<2048, 256, 0, stream>>>(h, lnfw, lnfb, (float*)d_out, 0);
  (void)in_sizes; (void)n_in; (void)out_size; (void)ws_size;
}